// Round 5
// baseline (474.457 us; speedup 1.0000x reference)
//
#include <hip/hip_runtime.h>
#include <hip/hip_bf16.h>
#include <hip/hip_cooperative_groups.h>
#include <math.h>

#define B_ 4
#define T_ 2048
#define C_ 768
#define H_ 12
#define D_ 64
#define R_ 64
#define BT_ (B_*T_)   /* 8192 */
#define HD_ (H_*D_)   /* 768  */

typedef __attribute__((ext_vector_type(8))) short bf16x8;
typedef __attribute__((ext_vector_type(4))) float f32x4;
typedef __attribute__((ext_vector_type(16))) float f32x16;

__device__ inline short f2bf(float f) {
  union { float f; unsigned u; } x; x.f = f;
  unsigned r = x.u + 0x7fffu + ((x.u >> 16) & 1u);
  return (short)(r >> 16);
}
__device__ inline unsigned pk_bf16(float a, float b) {
#if __has_builtin(__builtin_amdgcn_cvt_pk_bf16_f32)
  auto t = __builtin_amdgcn_cvt_pk_bf16_f32(a, b);
  unsigned u; __builtin_memcpy(&u, &t, sizeof(unsigned)); return u;
#else
  union { float f; unsigned u; } x, y; x.f = a; y.f = b;
  unsigned ra = (x.u + 0x7fffu + ((x.u >> 16) & 1u)) >> 16;
  unsigned rb = (y.u + 0x7fffu + ((y.u >> 16) & 1u)) & 0xffff0000u;
  return ra | rb;
#endif
}
__device__ inline float fexp2(float x) {
#if __has_builtin(__builtin_amdgcn_exp2f)
  return __builtin_amdgcn_exp2f(x);
#else
  return exp2f(x);
#endif
}
// cross-half (lane i <-> lane i+32) word swap
__device__ inline void pswap(unsigned &a, unsigned &b) {
#if __has_builtin(__builtin_amdgcn_permlane32_swap)
  auto r = __builtin_amdgcn_permlane32_swap((int)a, (int)b, false, false);
  unsigned u[2]; __builtin_memcpy(u, &r, 8);
  a = u[0]; b = u[1];
#else
  unsigned ax = __shfl_xor(a, 32), bx = __shfl_xor(b, 32);
  bool hi = (threadIdx.x & 32) != 0;
  unsigned na = hi ? bx : a;
  unsigned nb = hi ? b : ax;
  a = na; b = nb;
#endif
}
typedef __attribute__((address_space(3))) unsigned lds_u32;
typedef __attribute__((address_space(1))) const unsigned glb_u32;
__device__ inline void gload_lds16(const void* g, void* l) {
  __builtin_amdgcn_global_load_lds((glb_u32*)g, (lds_u32*)l, 16, 0, 0);
}

#define SC2_ 0.18033688f   /* 0.125 * log2(e) */

// ================= phase bodies (shared by mega kernel and fallback) =========

// ---- P0: weight transposes + rope table; unit in [0,1360) ----
__device__ __attribute__((always_inline)) inline void ttile(
    const float* __restrict__ src, short* __restrict__ dst,
    int K, int N, int k0, int n0, int tid, float (*tl)[33]) {
  int tx = tid & 31, ty = tid >> 5;
  #pragma unroll
  for (int r = 0; r < 4; ++r)
    tl[ty + 8 * r][tx] = src[(size_t)(k0 + ty + 8 * r) * N + n0 + tx];
  __syncthreads();
  #pragma unroll
  for (int r = 0; r < 4; ++r)
    dst[(size_t)(n0 + ty + 8 * r) * K + k0 + tx] = f2bf(tl[tx][ty + 8 * r]);
}

__device__ __attribute__((always_inline)) inline void prep_unit(
    int blk, int tid, char* smemc,
    const float* Wq, const float* Wd, const float* Wup, const float* Wo,
    short* W1T, short* WupT, short* WoT, float* cs, float* sn) {
  float (*tl)[33] = (float(*)[33])smemc;
  if (blk < 576) {                    // Wq: K=768,N=768 -> W1T rows 0..767
    int tk = blk % 24, tn = blk / 24;
    ttile(Wq, W1T, 768, 768, tk * 32, tn * 32, tid, tl);
  } else if (blk < 624) {             // Wd: K=768,N=64 -> W1T rows 768..831
    int l = blk - 576; int tk = l % 24, tn = l / 24;
    ttile(Wd, W1T + (size_t)768 * 768, 768, 64, tk * 32, tn * 32, tid, tl);
  } else if (blk < 720) {             // Wup: K=64,N=1536
    int l = blk - 624; int tk = l % 2, tn = l / 2;
    ttile(Wup, WupT, 64, 1536, tk * 32, tn * 32, tid, tl);
  } else if (blk < 1296) {            // Wo: K=768,N=768
    int l = blk - 720; int tk = l % 24, tn = l / 24;
    ttile(Wo, WoT, 768, 768, tk * 32, tn * 32, tid, tl);
  } else {                            // rope table
    int base = (blk - 1296) * 1024;
    #pragma unroll
    for (int i = 0; i < 4; ++i) {
      int idx = base + tid + i * 256;
      int j = idx & 31, t = idx >> 5;
      float invf = exp2f(-(float)j * (13.287712379549449f / 32.f)); // 10000^(-j/32)
      float a = (float)t * invf;
      cs[idx] = cosf(a);
      sn[idx] = sinf(a);
    }
  }
}

// ---- 128x128 GEMM body (m97 structure), MODE 0 dbuf + fused fp32 convert ----
// MODE 0 (A = x fp32; Bt = W1T 896 rows, N=832): cb<768 -> q*SC2+rope;
//   cb==768 -> LN(ckv); cb==832 -> garbage tile, skipped.
// MODE 1 (A = ckv bf16, K=64, single step): cb<768 -> k+rope; else v^T.
template<int MODE>
__device__ __attribute__((always_inline)) inline void gemm128_body(
    int m0, int n0, char* smemc,
    const float* __restrict__ Af, const short* __restrict__ Ab,
    const short* __restrict__ Bt, int K,
    const float* __restrict__ bias, const float* __restrict__ bias2,
    short* __restrict__ ob0, short* __restrict__ ob1,
    const float* __restrict__ cs, const float* __restrict__ sn)
{
  short* SM = (short*)smemc;
  const int tid = threadIdx.x, lane = tid & 63, w = tid >> 6;
  const int wr = w >> 1, wc = w & 1;
  const int fr = lane & 15, fk = (lane >> 4) * 8;
  const int rstage = lane >> 3;
  const int cstage = (lane & 7) * 8;

  f32x4 acc[4][4] = {};

  auto As = [&](int buf) -> short* { return SM + buf * 16384; };
  auto Bs = [&](int buf) -> short* { return SM + buf * 16384 + 8192; };

  auto compute = [&](const short* Asb, const short* Bsb) {
    #pragma unroll
    for (int kk = 0; kk < 64; kk += 32) {
      bf16x8 a[4], b[4];
      #pragma unroll
      for (int mi = 0; mi < 4; ++mi)
        a[mi] = *(const bf16x8*)&Asb[(wr * 64 + mi * 16 + fr) * 64 + kk + fk];
      #pragma unroll
      for (int ni = 0; ni < 4; ++ni)
        b[ni] = *(const bf16x8*)&Bsb[(wc * 64 + ni * 16 + fr) * 64 + kk + fk];
      #pragma unroll
      for (int mi = 0; mi < 4; ++mi)
        #pragma unroll
        for (int ni = 0; ni < 4; ++ni)
          acc[mi][ni] = __builtin_amdgcn_mfma_f32_16x16x32_bf16(a[mi], b[ni], acc[mi][ni], 0, 0, 0);
    }
  };

  auto stageB = [&](short* Bsb, int k0) {
    #pragma unroll
    for (int i = 0; i < 4; ++i) {
      int c = w * 4 + i;
      int r = c * 8 + rstage;
      gload_lds16(&Bt[(size_t)(n0 + r) * K + k0 + cstage], Bsb + c * 512);
    }
  };

  if constexpr (MODE == 0) {
    float4 fa[8];
    auto loadA = [&](int k0) {
      #pragma unroll
      for (int i = 0; i < 4; ++i) {
        int idx = tid + 256 * i;
        int row = idx >> 3, c8 = idx & 7;
        const float* src = Af + (size_t)(m0 + row) * 768 + k0 + c8 * 8;
        fa[2 * i]     = *(const float4*)(src);
        fa[2 * i + 1] = *(const float4*)(src + 4);
      }
    };
    auto writeA = [&](short* Asb) {
      #pragma unroll
      for (int i = 0; i < 4; ++i) {
        int idx = tid + 256 * i;
        int row = idx >> 3, c8 = idx & 7;
        uint4 uu;
        uu.x = pk_bf16(fa[2 * i].x,     fa[2 * i].y);
        uu.y = pk_bf16(fa[2 * i].z,     fa[2 * i].w);
        uu.z = pk_bf16(fa[2 * i + 1].x, fa[2 * i + 1].y);
        uu.w = pk_bf16(fa[2 * i + 1].z, fa[2 * i + 1].w);
        *(uint4*)&Asb[row * 64 + c8 * 8] = uu;
      }
    };

    loadA(0);
    stageB(Bs(0), 0);
    writeA(As(0));
    __syncthreads();

    int buf = 0;
    for (int k0 = 0; k0 < K; k0 += 64) {
      bool nxt = (k0 + 64 < K);
      if (nxt) { loadA(k0 + 64); stageB(Bs(buf ^ 1), k0 + 64); }
      compute(As(buf), Bs(buf));
      if (nxt) writeA(As(buf ^ 1));
      __syncthreads();
      buf ^= 1;
    }
  } else {
    #pragma unroll
    for (int i = 0; i < 4; ++i) {
      int c = w * 4 + i;
      int r = c * 8 + rstage;
      gload_lds16(&Ab[(size_t)(m0 + r) * K + cstage], As(0) + c * 512);
      gload_lds16(&Bt[(size_t)(n0 + r) * K + cstage], Bs(0) + c * 512);
    }
    __syncthreads();
    compute(As(0), Bs(0));
  }

  const int er = (lane >> 4) * 4, ec = lane & 15;
  const int cb = n0 + wc * 64;        // this wave's 64-col base

  if (cb < 768) {  // q (MODE0) or k (MODE1), fused RoPE (+ SC2 scale for q)
    int h = cb >> 6;
    #pragma unroll
    for (int mi = 0; mi < 4; ++mi)
      #pragma unroll
      for (int r = 0; r < 4; ++r) {
        int row = m0 + wr * 64 + mi * 16 + er + r;
        int t = row & (T_ - 1), bb = row >> 11;
        short* dst = ob0 + (((size_t)(bb * H_ + h)) * T_ + t) * 64;
        #pragma unroll
        for (int ni = 0; ni < 2; ++ni) {
          int d = ni * 16 + ec;
          float c = cs[t * 32 + d], s = sn[t * 32 + d];
          if constexpr (MODE == 0) { c *= SC2_; s *= SC2_; }
          float x0 = acc[mi][ni][r], x1 = acc[mi][ni + 2][r];
          dst[d]      = f2bf(x0 * c - x1 * s);
          dst[d + 32] = f2bf(x1 * c + x0 * s);
        }
      }
  } else if constexpr (MODE == 0) {
    if (cb == 768) {   // fused LayerNorm (bias=ln_g, bias2=ln_b)
      #pragma unroll
      for (int mi = 0; mi < 4; ++mi)
        #pragma unroll
        for (int r = 0; r < 4; ++r) {
          float s = 0.f, s2 = 0.f;
          #pragma unroll
          for (int ni = 0; ni < 4; ++ni) { float v = acc[mi][ni][r]; s += v; s2 += v*v; }
          #pragma unroll
          for (int off = 1; off < 16; off <<= 1) {
            s  += __shfl_xor(s, off);
            s2 += __shfl_xor(s2, off);
          }
          float mu = s * (1.f/64.f);
          float var = s2 * (1.f/64.f) - mu * mu;
          float rstd = rsqrtf(var + 1e-5f);
          int row = m0 + wr * 64 + mi * 16 + er + r;
          #pragma unroll
          for (int ni = 0; ni < 4; ++ni) {
            int d = ni * 16 + ec;
            ob1[(size_t)row * 64 + d] = f2bf((acc[mi][ni][r] - mu) * rstd * bias[d] + bias2[d]);
          }
        }
    }
  } else {
    // MODE 1 v tile: acc -> wave-private LDS (stride 40) -> coalesced vt
    __syncthreads();   // all waves done reading As/Bs
    short* Wl = SM + w * 2560;     // 64 d-rows x 40 shorts, per wave
    int h = (cb - 768) >> 6;
    int bb = m0 >> 11;
    int dl = lane >> 2, tl = (lane & 3) * 8;
    #pragma unroll
    for (int hp = 0; hp < 2; ++hp) {
      #pragma unroll
      for (int mi2 = 0; mi2 < 2; ++mi2) {
        int mi = hp * 2 + mi2;
        int tl0 = mi2 * 16 + er;
        #pragma unroll
        for (int ni = 0; ni < 4; ++ni) {
          int d = ni * 16 + ec;
          uint2 uu;
          uu.x = pk_bf16(acc[mi][ni][0], acc[mi][ni][1]);
          uu.y = pk_bf16(acc[mi][ni][2], acc[mi][ni][3]);
          *(uint2*)&Wl[d * 40 + tl0] = uu;
        }
      }
      int tg0 = (m0 & (T_ - 1)) + wr * 64 + hp * 32;
      #pragma unroll
      for (int j = 0; j < 4; ++j) {
        int d = j * 16 + dl;
        uint4 vv = *(const uint4*)&Wl[d * 40 + tl];
        *(uint4*)&ob1[((size_t)(bb * H_ + h) * 64 + d) * T_ + tg0 + tl] = vv;
      }
    }
  }
}

// ---- out = att @ Wo + bo: 128x64 tile, double-buffered (48KB) ----
__device__ __attribute__((always_inline)) inline void gemmout_body(
    int m0, int n0, char* smemc,
    const short* __restrict__ A, const short* __restrict__ Bt,
    float* __restrict__ out0, const float* __restrict__ bias)
{
  short* SM = (short*)smemc;
  const int K = HD_, N = C_;
  const int tid = threadIdx.x, lane = tid & 63, w = tid >> 6;
  const int fr = lane & 15, fk = (lane >> 4) * 8;
  const int rstage = lane >> 3;
  const int cstage = (lane & 7) * 8;

  f32x4 acc[2][4] = {};

  auto As = [&](int buf) -> short* { return SM + buf * 12288; };
  auto Bs = [&](int buf) -> short* { return SM + buf * 12288 + 8192; };

  auto stage = [&](int buf, int k0) {
    #pragma unroll
    for (int i = 0; i < 4; ++i) {
      int c = w * 4 + i;
      int r = c * 8 + rstage;
      gload_lds16(&A[(size_t)(m0 + r) * K + k0 + cstage], As(buf) + c * 512);
    }
    #pragma unroll
    for (int i = 0; i < 2; ++i) {
      int c = w * 2 + i;
      int r = c * 8 + rstage;
      gload_lds16(&Bt[(size_t)(n0 + r) * K + k0 + cstage], Bs(buf) + c * 512);
    }
  };

  stage(0, 0);
  __syncthreads();

  int buf = 0;
  for (int k0 = 0; k0 < K; k0 += 64) {
    if (k0 + 64 < K) stage(buf ^ 1, k0 + 64);
    #pragma unroll
    for (int kk = 0; kk < 64; kk += 32) {
      bf16x8 a[2], b[4];
      a[0] = *(const bf16x8*)&As(buf)[(w * 32 +      fr) * 64 + kk + fk];
      a[1] = *(const bf16x8*)&As(buf)[(w * 32 + 16 + fr) * 64 + kk + fk];
      #pragma unroll
      for (int ni = 0; ni < 4; ++ni)
        b[ni] = *(const bf16x8*)&Bs(buf)[(ni * 16 + fr) * 64 + kk + fk];
      #pragma unroll
      for (int mi = 0; mi < 2; ++mi)
        #pragma unroll
        for (int ni = 0; ni < 4; ++ni)
          acc[mi][ni] = __builtin_amdgcn_mfma_f32_16x16x32_bf16(a[mi], b[ni], acc[mi][ni], 0, 0, 0);
    }
    __syncthreads();
    buf ^= 1;
  }

  const int er = (lane >> 4) * 4, ec = lane & 15;
  #pragma unroll
  for (int mi = 0; mi < 2; ++mi)
    #pragma unroll
    for (int r = 0; r < 4; ++r) {
      int row = m0 + w * 32 + mi * 16 + er + r;
      #pragma unroll
      for (int ni = 0; ni < 4; ++ni) {
        int col = n0 + ni * 16 + ec;
        out0[(size_t)row * N + col] = acc[mi][ni][r] + bias[col];
      }
    }
}

// ---- attn body (v9, verified): unit = (bh, u) ----
// Balanced waves: wave w owns q-tile 4u+w (ranges {2u+1,2u+1,2u+2,2u+2}).
// Double-buffered K/V staging, in-register P via cvt_pk+permlane32_swap,
// deferred l-reduction, setprio around MFMA.
// 32x32 C/D layout (m74/m101): col=lane&31, row=(reg&3)+8*(reg>>2)+4*(lane>>5).
__device__ __attribute__((always_inline)) inline void attn_body(
    int bh, int u, char* smemc,
    const short* __restrict__ qgl, const short* __restrict__ kg,
    const short* __restrict__ vtg, short* __restrict__ o)
{
  typedef short KVBUF[2][8 * 512];
  KVBUF* SMa = (KVBUF*)smemc;          // [2 buf][2 kv][4096]

  const int tid = threadIdx.x, lane = tid & 63, w = tid >> 6;
  const int q32 = lane & 31, half = lane >> 5;
  const short* kb  = kg  + (size_t)bh * T_ * 64;
  const short* vtb = vtg + (size_t)bh * 64 * T_;
  const int b = bh / H_, h = bh - b * H_;

  const int wq = 4 * u + w;            // this wave's 32-row q-tile (0..63)
  const int q0 = wq * 32;
  const int last_w = (wq >> 1) * 64;   // diagonal k-tile start for this wave
  const int qidx = q0 + q32;
  const int kend = (2 * u + 1) * 64;   // block stages k-tiles 0..2u+1

  const short* qrow = qgl + ((size_t)bh * T_ + qidx) * 64;
  bf16x8 bq[4];
  #pragma unroll
  for (int ks = 0; ks < 4; ++ks)
    bq[ks] = *(const bf16x8*)&qrow[ks * 16 + half * 8];

  f32x16 oacc[2] = {};
  float lrun = 0.f;

  auto stage = [&](int buf, int kt) {
    #pragma unroll
    for (int i = 0; i < 2; ++i) {      // wave w stages chunks {2w, 2w+1}
      int c = w * 2 + i;
      int kh = c >> 2, ks = c & 3;
      gload_lds16(kb + (size_t)(kt + kh * 32 + q32) * 64 + ks * 16 + half * 8,
                  &SMa[buf][0][c * 512]);
      gload_lds16(vtb + (size_t)(kh * 32 + q32) * T_ + kt + ks * 16 + half * 8,
                  &SMa[buf][1][c * 512]);
    }
  };

  stage(0, 0);
  __syncthreads();                     // buf0 ready

  int cur = 0;
  for (int kt = 0; kt <= kend; kt += 64) {
    if (kt + 64 <= kend) stage(cur ^ 1, kt + 64);   // async prefetch next tile

    if (kt <= last_w) {
      const short* Kc = &SMa[cur][0][0];
      const short* Vc = &SMa[cur][1][0];
      const bool diag = (kt == last_w);
      const int dkh = diag ? (wq & 1) : 2;  // which kh is diagonal-masked
      const bool skip1 = diag && ((wq & 1) == 0);

      bf16x8 bp[4];
      #pragma unroll
      for (int kh = 0; kh < 2; ++kh) {
        if (kh == 1 && skip1) break;    // fully-masked upper half of diag tile
        f32x16 sacc = {};
        __builtin_amdgcn_s_setprio(1);
        #pragma unroll
        for (int ks = 0; ks < 4; ++ks) {
          bf16x8 a = *(const bf16x8*)&Kc[(kh * 4 + ks) * 512 + lane * 8];
          sacc = __builtin_amdgcn_mfma_f32_32x32x16_bf16(a, bq[ks], sacc, 0, 0, 0);
        }
        __builtin_amdgcn_s_setprio(0);
        float pv[16];
        if (kh != dkh) {
          #pragma unroll
          for (int r = 0; r < 16; ++r) pv[r] = fexp2(sacc[r]);
        } else {
          #pragma unroll
          for (int r = 0; r < 16; ++r) {
            int key = kt + kh * 32 + (r & 3) + 8 * (r >> 2) + 4 * half;
            pv[r] = (key <= qidx) ? fexp2(sacc[r]) : 0.f;
          }
        }
        float t0 = (pv[0] + pv[1]) + (pv[2] + pv[3]);
        float t1 = (pv[4] + pv[5]) + (pv[6] + pv[7]);
        float t2 = (pv[8] + pv[9]) + (pv[10] + pv[11]);
        float t3 = (pv[12] + pv[13]) + (pv[14] + pv[15]);
        lrun += (t0 + t1) + (t2 + t3);
        unsigned l0 = pk_bf16(pv[0],  pv[1]),  h0 = pk_bf16(pv[2],  pv[3]);
        unsigned l1 = pk_bf16(pv[4],  pv[5]),  h1 = pk_bf16(pv[6],  pv[7]);
        unsigned l2 = pk_bf16(pv[8],  pv[9]),  h2 = pk_bf16(pv[10], pv[11]);
        unsigned l3 = pk_bf16(pv[12], pv[13]), h3 = pk_bf16(pv[14], pv[15]);
        pswap(l0, l1); pswap(h0, h1);
        pswap(l2, l3); pswap(h2, h3);
        union { unsigned u[4]; bf16x8 v; } f0, f1;
        f0.u[0] = l0; f0.u[1] = h0; f0.u[2] = l1; f0.u[3] = h1;
        f1.u[0] = l2; f1.u[1] = h2; f1.u[2] = l3; f1.u[3] = h3;
        bp[2 * kh + 0] = f0.v;
        bp[2 * kh + 1] = f1.v;
      }

      __builtin_amdgcn_s_setprio(1);
      #pragma unroll
      for (int ks = 0; ks < 2; ++ks)
        #pragma unroll
        for (int dt = 0; dt < 2; ++dt) {
          bf16x8 av = *(const bf16x8*)&Vc[(dt * 4 + ks) * 512 + lane * 8];
          oacc[dt] = __builtin_amdgcn_mfma_f32_32x32x16_bf16(av, bp[ks], oacc[dt], 0, 0, 0);
        }
      if (!skip1) {
        #pragma unroll
        for (int ks = 2; ks < 4; ++ks)
          #pragma unroll
          for (int dt = 0; dt < 2; ++dt) {
            bf16x8 av = *(const bf16x8*)&Vc[(dt * 4 + ks) * 512 + lane * 8];
            oacc[dt] = __builtin_amdgcn_mfma_f32_32x32x16_bf16(av, bp[ks], oacc[dt], 0, 0, 0);
          }
      }
      __builtin_amdgcn_s_setprio(0);
    }

    __syncthreads();
    cur ^= 1;
  }

  float ltot = lrun + __shfl_xor(lrun, 32);
  float inv = 1.f / ltot;
  short* Pw = (short*)smemc + w * 2304;   // 32 rows x 72 shorts per wave
  #pragma unroll
  for (int dt = 0; dt < 2; ++dt)
    #pragma unroll
    for (int g2 = 0; g2 < 4; ++g2) {
      uint2 uu;
      uu.x = pk_bf16(oacc[dt][4 * g2 + 0] * inv, oacc[dt][4 * g2 + 1] * inv);
      uu.y = pk_bf16(oacc[dt][4 * g2 + 2] * inv, oacc[dt][4 * g2 + 3] * inv);
      *(uint2*)&Pw[q32 * 72 + dt * 32 + 8 * g2 + 4 * half] = uu;
    }
  int row = lane >> 1, seg = lane & 1;
  int t = q0 + row;
  short* orow = o + ((size_t)(b * T_ + t)) * HD_ + h * 64 + seg * 32;
  #pragma unroll
  for (int i = 0; i < 4; ++i) {
    uint4 vv = *(const uint4*)&Pw[row * 72 + seg * 32 + i * 8];
    *(uint4*)&orow[i * 8] = vv;
  }
}

// ================= mega kernel (cooperative, 5 phases) =======================
struct MegaArgs {
  const float *x, *Wq, *Wd, *ln_g, *ln_b, *Wup, *Wo, *bo;
  float *out;
  short *W1T, *WupT, *WoT, *ckv, *qb, *kb, *vt, *att;
  float *cs, *sn;
  unsigned *qcnt;
};

namespace cg = cooperative_groups;

__global__ __launch_bounds__(256, 2) void mega(MegaArgs A) {
  __shared__ __align__(16) char SMEM[65536];
  const int blk = blockIdx.x;      // 0..511
  const int tid = threadIdx.x;
  cg::grid_group grid = cg::this_grid();

  if (blk == 0 && tid == 0) *A.qcnt = 0u;

  // P0: prep (weight transposes + rope), 1360 units
  for (int p = blk; p < 1360; p += 512) {
    prep_unit(p, tid, SMEM, A.Wq, A.Wd, A.Wup, A.Wo, A.W1T, A.WupT, A.WoT, A.cs, A.sn);
    __syncthreads();
  }
  grid.sync();

  // P1: gemm0 (q + LN(ckv)), 448 units (64x7)
  if (blk < 448) {
    int bx = blk & 63, by = blk >> 6;
    gemm128_body<0>(bx * 128, by * 128, SMEM, A.x, nullptr, A.W1T, 768,
                    A.ln_g, A.ln_b, A.qb, A.ckv, A.cs, A.sn);
  }
  grid.sync();

  // P2: gemm1 (k + v^T), 768 units (64x12)
  for (int p = blk; p < 768; p += 512) {
    int bx = p & 63, by = p >> 6;
    gemm128_body<1>(bx * 128, by * 128, SMEM, nullptr, A.ckv, A.WupT, 64,
                    nullptr, nullptr, A.kb, A.vt, A.cs, A.sn);
    __syncthreads();
  }
  grid.sync();

  // P3: attention, dynamic LPT work queue (768 units, longest u=15 first)
  unsigned* qslot = (unsigned*)(SMEM + 65532);   // attn uses only first 32KB
  for (;;) {
    __syncthreads();
    if (tid == 0) *qslot = atomicAdd(A.qcnt, 1u);
    __syncthreads();
    unsigned q = *qslot;
    if (q >= 768u) break;
    attn_body((int)(q % 48u), 15 - (int)(q / 48u), SMEM, A.qb, A.kb, A.vt, A.att);
  }
  grid.sync();

  // P4: out = att @ Wo + bo, 768 units (64x12)
  for (int p = blk; p < 768; p += 512) {
    int bx = p & 63, by = p >> 6;
    gemmout_body(bx * 128, by * 64, SMEM, A.att, A.WoT, A.out, A.bo);
    __syncthreads();
  }
}

// ================= fallback standalone kernels (R4 pipeline) =================
__global__ __launch_bounds__(256) void prep_conv_k(
    const float* Wq, const float* Wd, const float* Wup, const float* Wo,
    short* W1T, short* WupT, short* WoT, float* cs, float* sn) {
  __shared__ __align__(16) char s[4352];
  prep_unit(blockIdx.x, threadIdx.x, s, Wq, Wd, Wup, Wo, W1T, WupT, WoT, cs, sn);
}
__global__ __launch_bounds__(256) void gemm0_k(
    const float* x, const short* W1T, const float* ln_g, const float* ln_b,
    short* qb, short* ckv, const float* cs, const float* sn) {
  __shared__ __align__(16) char s[65536];
  gemm128_body<0>(blockIdx.x * 128, blockIdx.y * 128, s, x, nullptr, W1T, 768,
                  ln_g, ln_b, qb, ckv, cs, sn);
}
__global__ __launch_bounds__(256) void gemm1_k(
    const short* ckv, const short* WupT, short* kb, short* vt,
    const float* cs, const float* sn) {
  __shared__ __align__(16) char s[32768];
  gemm128_body<1>(blockIdx.x * 128, blockIdx.y * 128, s, nullptr, ckv, WupT, 64,
                  nullptr, nullptr, kb, vt, cs, sn);
}
__global__ __launch_bounds__(256) void attn_k(
    const short* qb, const short* kb, const short* vt, short* att) {
  __shared__ __align__(16) char s[32768];
  attn_body(blockIdx.x, 15 - (int)blockIdx.y, s, qb, kb, vt, att);
}
__global__ __launch_bounds__(256) void gemmout_k(
    const short* att, const short* WoT, float* out, const float* bo) {
  __shared__ __align__(16) char s[49152];
  gemmout_body(blockIdx.x * 128, blockIdx.y * 64, s, att, WoT, out, bo);
}

// ---------------- launcher ----------------
extern "C" void kernel_launch(void* const* d_in, const int* in_sizes, int n_in,
                              void* d_out, int out_size, void* d_ws, size_t ws_size,
                              hipStream_t stream) {
  (void)in_sizes; (void)n_in; (void)out_size; (void)ws_size;
  const float* x     = (const float*)d_in[0];
  const float* Wq    = (const float*)d_in[1];
  const float* Wdown = (const float*)d_in[2];
  const float* ln_g  = (const float*)d_in[3];
  const float* ln_b  = (const float*)d_in[4];
  const float* Wup   = (const float*)d_in[5];
  const float* Wo    = (const float*)d_in[6];
  const float* bo    = (const float*)d_in[7];
  float* out = (float*)d_out;

  char* w = (char*)d_ws;
  short* W1T    = (short*)w;  w += (size_t)896 * C_    * 2;  // 832 used + 64 pad rows
  short* WupT   = (short*)w;  w += (size_t)2*HD_ * R_  * 2;
  short* WoT    = (short*)w;  w += (size_t)HD_ * C_    * 2;
  short* ckv    = (short*)w;  w += (size_t)BT_ * R_    * 2;
  short* qb     = (short*)w;  w += (size_t)BT_ * HD_   * 2;
  short* kb     = (short*)w;  w += (size_t)BT_ * HD_   * 2;
  short* vt     = (short*)w;  w += (size_t)BT_ * HD_   * 2;
  short* att    = (short*)w;  w += (size_t)BT_ * HD_   * 2;
  float* cs_t   = (float*)w;  w += (size_t)T_ * 32 * 4;
  float* sn_t   = (float*)w;  w += (size_t)T_ * 32 * 4;
  unsigned* qcnt = (unsigned*)w; w += 64;

  MegaArgs ma;
  ma.x = x; ma.Wq = Wq; ma.Wd = Wdown; ma.ln_g = ln_g; ma.ln_b = ln_b;
  ma.Wup = Wup; ma.Wo = Wo; ma.bo = bo; ma.out = out;
  ma.W1T = W1T; ma.WupT = WupT; ma.WoT = WoT; ma.ckv = ckv;
  ma.qb = qb; ma.kb = kb; ma.vt = vt; ma.att = att;
  ma.cs = cs_t; ma.sn = sn_t; ma.qcnt = qcnt;
  void* kargs[] = { &ma };

  hipError_t e = hipLaunchCooperativeKernel((const void*)mega, dim3(512), dim3(256),
                                            kargs, 0, stream);
  if (e != hipSuccess) {
    // fallback: R4 5-kernel pipeline (identical phase bodies)
    prep_conv_k<<<1360, 256, 0, stream>>>(Wq, Wdown, Wup, Wo, W1T, WupT, WoT, cs_t, sn_t);
    gemm0_k<<<dim3(64, 7), 256, 0, stream>>>(x, W1T, ln_g, ln_b, qb, ckv, cs_t, sn_t);
    gemm1_k<<<dim3(64, 12), 256, 0, stream>>>(ckv, WupT, kb, vt, cs_t, sn_t);
    attn_k<<<dim3(48, 16), 256, 0, stream>>>(qb, kb, vt, att);
    gemmout_k<<<dim3(64, 12), 256, 0, stream>>>(att, WoT, out, bo);
  }
}

// Round 6
// 195.663 us; speedup vs baseline: 2.4249x; 2.4249x over previous
//
#include <hip/hip_runtime.h>
#include <hip/hip_bf16.h>
#include <math.h>

#define B_ 4
#define T_ 2048
#define C_ 768
#define H_ 12
#define D_ 64
#define R_ 64
#define BT_ (B_*T_)   /* 8192 */
#define HD_ (H_*D_)   /* 768  */

typedef __attribute__((ext_vector_type(8))) short bf16x8;
typedef __attribute__((ext_vector_type(4))) float f32x4;
typedef __attribute__((ext_vector_type(16))) float f32x16;

__device__ inline short f2bf(float f) {
  union { float f; unsigned u; } x; x.f = f;
  unsigned r = x.u + 0x7fffu + ((x.u >> 16) & 1u);
  return (short)(r >> 16);
}
__device__ inline unsigned pk_bf16(float a, float b) {
#if __has_builtin(__builtin_amdgcn_cvt_pk_bf16_f32)
  auto t = __builtin_amdgcn_cvt_pk_bf16_f32(a, b);
  unsigned u; __builtin_memcpy(&u, &t, sizeof(unsigned)); return u;
#else
  union { float f; unsigned u; } x, y; x.f = a; y.f = b;
  unsigned ra = (x.u + 0x7fffu + ((x.u >> 16) & 1u)) >> 16;
  unsigned rb = (y.u + 0x7fffu + ((y.u >> 16) & 1u)) & 0xffff0000u;
  return ra | rb;
#endif
}
__device__ inline float fexp2(float x) {
#if __has_builtin(__builtin_amdgcn_exp2f)
  return __builtin_amdgcn_exp2f(x);
#else
  return exp2f(x);
#endif
}
// cross-half (lane i <-> lane i+32) word swap
__device__ inline void pswap(unsigned &a, unsigned &b) {
#if __has_builtin(__builtin_amdgcn_permlane32_swap)
  auto r = __builtin_amdgcn_permlane32_swap((int)a, (int)b, false, false);
  unsigned u[2]; __builtin_memcpy(u, &r, 8);
  a = u[0]; b = u[1];
#else
  unsigned ax = __shfl_xor(a, 32), bx = __shfl_xor(b, 32);
  bool hi = (threadIdx.x & 32) != 0;
  unsigned na = hi ? bx : a;
  unsigned nb = hi ? b : ax;
  a = na; b = nb;
#endif
}
typedef __attribute__((address_space(3))) unsigned lds_u32;
typedef __attribute__((address_space(1))) const unsigned glb_u32;
__device__ inline void gload_lds16(const void* g, void* l) {
  __builtin_amdgcn_global_load_lds((glb_u32*)g, (lds_u32*)l, 16, 0, 0);
}

#define SC2_ 0.18033688f   /* 0.125 * log2(e) */

// ---------------- prep: weight transposes + Wvo = Wuv_h @ Wo_h + rope table --
// Units: [0,576) Wq->W1T | [576,624) Wdown->W1T rows 768.. | [624,672)
// Wup[:, :768] -> WupT | [672,1248) Wvo compute | [1248,1312) rope.
__device__ __attribute__((always_inline)) inline void ttile(
    const float* __restrict__ src, short* __restrict__ dst,
    int Kd, int Ns, int k0, int n0, int tid, float (*tl)[33]) {
  // Kd = dst row stride (src rows), Ns = src row stride
  int tx = tid & 31, ty = tid >> 5;
  #pragma unroll
  for (int r = 0; r < 4; ++r)
    tl[ty + 8 * r][tx] = src[(size_t)(k0 + ty + 8 * r) * Ns + n0 + tx];
  __syncthreads();
  #pragma unroll
  for (int r = 0; r < 4; ++r)
    dst[(size_t)(n0 + ty + 8 * r) * Kd + k0 + tx] = f2bf(tl[tx][ty + 8 * r]);
}

__global__ __launch_bounds__(256) void prep_conv(
    const float* __restrict__ Wq, const float* __restrict__ Wd,
    const float* __restrict__ Wup, const float* __restrict__ Wo,
    short* __restrict__ W1T, short* __restrict__ WupT, short* __restrict__ WvoT,
    float* __restrict__ cs, float* __restrict__ sn) {
  __shared__ float SH[32 * 65 + 64 * 33];   // 16.8 KB arena
  float (*tl)[33] = (float(*)[33])SH;
  int tid = threadIdx.x, blk = blockIdx.x;
  if (blk < 576) {                    // Wq: [768][768] -> W1T rows 0..767
    int tk = blk % 24, tn = blk / 24;
    ttile(Wq, W1T, 768, 768, tk * 32, tn * 32, tid, tl);
  } else if (blk < 624) {             // Wdown: [768][64] -> W1T rows 768..831
    int l = blk - 576; int tk = l % 24, tn = l / 24;
    ttile(Wd, W1T + (size_t)768 * 768, 768, 64, tk * 32, tn * 32, tid, tl);
  } else if (blk < 672) {             // Wup k-half: [64][1536], cols 0..767
    int l = blk - 624; int tk = l % 2, tn = l / 2;
    ttile(Wup, WupT, 64, 1536, tk * 32, tn * 32, tid, tl);
  } else if (blk < 1248) {            // Wvo_h = Wuv_h[64x64] @ Wo_h[64x768]
    int l = blk - 672;
    int h = l / 48, rem = l % 48, tc = rem >> 1, tr = rem & 1;
    float* a  = SH;                   // [32][65] Wuv rows (padded: no bank dup)
    float* bm = SH + 32 * 65;         // [64][33] Wo cols
    #pragma unroll
    for (int i = 0; i < 8; ++i) {
      int idx = tid + i * 256;
      int r = idx >> 6, d = idx & 63;
      a[r * 65 + d] = Wup[(size_t)(tr * 32 + r) * 1536 + 768 + h * 64 + d];
      int dd = idx >> 5, c = idx & 31;
      bm[dd * 33 + c] = Wo[(size_t)(h * 64 + dd) * 768 + tc * 32 + c];
    }
    __syncthreads();
    int r = tid & 31, cj = tid >> 5;            // cj in [0,8): 4 cols each
    float s0 = 0.f, s1 = 0.f, s2 = 0.f, s3 = 0.f;
    #pragma unroll
    for (int d = 0; d < 64; ++d) {
      float av = a[r * 65 + d];
      const float* bp = &bm[d * 33 + cj * 4];
      s0 += av * bp[0]; s1 += av * bp[1]; s2 += av * bp[2]; s3 += av * bp[3];
    }
    int colb = tc * 32 + cj * 4;
    size_t krow = (size_t)(h * 64 + tr * 32 + r);
    WvoT[(size_t)(colb + 0) * 768 + krow] = f2bf(s0);
    WvoT[(size_t)(colb + 1) * 768 + krow] = f2bf(s1);
    WvoT[(size_t)(colb + 2) * 768 + krow] = f2bf(s2);
    WvoT[(size_t)(colb + 3) * 768 + krow] = f2bf(s3);
  } else {                            // rope table, 64 units x 1024
    int base = (blk - 1248) * 1024;
    #pragma unroll
    for (int i = 0; i < 4; ++i) {
      int idx = base + tid + i * 256;
      int j = idx & 31, t = idx >> 5;
      float invf = exp2f(-(float)j * (13.287712379549449f / 32.f)); // 10000^(-j/32)
      float ang = (float)t * invf;
      cs[idx] = cosf(ang);
      sn[idx] = sinf(ang);
    }
  }
}

// ---------------- gemm0: x(fp32) @ [Wq|Wdown|pad] (dbuf, fused convert) ------
// 128x128 tile, waves 2x2, wave (wr,wc) owns a 64x64 quadrant (= one head).
// cb<768 -> q*SC2+rope -> qb [BH][T][64]; cb==768 -> LN -> ckv [M][64] AND
// ckvT [B][64][T] (wave-LDS stride-40 transpose); cb==832 -> garbage, skip.
__global__ __launch_bounds__(256) void gemm0_k(
    const float* __restrict__ Af, const short* __restrict__ Bt,
    const float* __restrict__ bias, const float* __restrict__ bias2,
    short* __restrict__ ob0, short* __restrict__ ob1, short* __restrict__ obT,
    const float* __restrict__ cs, const float* __restrict__ sn)
{
  constexpr int K = 768;
  __shared__ short SM[2 * 16384];       // dbuf x (As 16KB | Bs 16KB) = 64KB
  const int m0 = blockIdx.x * 128;
  const int n0 = blockIdx.y * 128;
  const int tid = threadIdx.x, lane = tid & 63, w = tid >> 6;
  const int wr = w >> 1, wc = w & 1;
  const int fr = lane & 15, fk = (lane >> 4) * 8;
  const int rstage = lane >> 3, cstage = (lane & 7) * 8;

  f32x4 acc[4][4] = {};
  auto As = [&](int buf) -> short* { return SM + buf * 16384; };
  auto Bs = [&](int buf) -> short* { return SM + buf * 16384 + 8192; };

  auto compute = [&](const short* Asb, const short* Bsb) {
    #pragma unroll
    for (int kk = 0; kk < 64; kk += 32) {
      bf16x8 a[4], b[4];
      #pragma unroll
      for (int mi = 0; mi < 4; ++mi)
        a[mi] = *(const bf16x8*)&Asb[(wr * 64 + mi * 16 + fr) * 64 + kk + fk];
      #pragma unroll
      for (int ni = 0; ni < 4; ++ni)
        b[ni] = *(const bf16x8*)&Bsb[(wc * 64 + ni * 16 + fr) * 64 + kk + fk];
      #pragma unroll
      for (int mi = 0; mi < 4; ++mi)
        #pragma unroll
        for (int ni = 0; ni < 4; ++ni)
          acc[mi][ni] = __builtin_amdgcn_mfma_f32_16x16x32_bf16(a[mi], b[ni], acc[mi][ni], 0, 0, 0);
    }
  };
  auto stageB = [&](short* Bsb, int k0) {
    #pragma unroll
    for (int i = 0; i < 4; ++i) {
      int c = w * 4 + i;
      int r = c * 8 + rstage;
      gload_lds16(&Bt[(size_t)(n0 + r) * K + k0 + cstage], Bsb + c * 512);
    }
  };

  float4 fa[8];
  auto loadA = [&](int k0) {
    #pragma unroll
    for (int i = 0; i < 4; ++i) {
      int idx = tid + 256 * i;
      int row = idx >> 3, c8 = idx & 7;
      const float* src = Af + (size_t)(m0 + row) * 768 + k0 + c8 * 8;
      fa[2 * i]     = *(const float4*)(src);
      fa[2 * i + 1] = *(const float4*)(src + 4);
    }
  };
  auto writeA = [&](short* Asb) {
    #pragma unroll
    for (int i = 0; i < 4; ++i) {
      int idx = tid + 256 * i;
      int row = idx >> 3, c8 = idx & 7;
      uint4 uu;
      uu.x = pk_bf16(fa[2 * i].x,     fa[2 * i].y);
      uu.y = pk_bf16(fa[2 * i].z,     fa[2 * i].w);
      uu.z = pk_bf16(fa[2 * i + 1].x, fa[2 * i + 1].y);
      uu.w = pk_bf16(fa[2 * i + 1].z, fa[2 * i + 1].w);
      *(uint4*)&Asb[row * 64 + c8 * 8] = uu;
    }
  };

  loadA(0);
  stageB(Bs(0), 0);
  writeA(As(0));
  __syncthreads();

  int buf = 0;
  for (int k0 = 0; k0 < K; k0 += 64) {
    bool nxt = (k0 + 64 < K);
    if (nxt) { loadA(k0 + 64); stageB(Bs(buf ^ 1), k0 + 64); }
    compute(As(buf), Bs(buf));
    if (nxt) writeA(As(buf ^ 1));
    __syncthreads();
    buf ^= 1;
  }
  // after the final barrier no wave reads SM again -> LN waves may reuse it.

  const int er = (lane >> 4) * 4, ec = lane & 15;
  const int cb = n0 + wc * 64;

  if (cb < 768) {  // q: fused SC2 scale + rope
    int h = cb >> 6;
    #pragma unroll
    for (int mi = 0; mi < 4; ++mi)
      #pragma unroll
      for (int r = 0; r < 4; ++r) {
        int row = m0 + wr * 64 + mi * 16 + er + r;
        int t = row & (T_ - 1), bb = row >> 11;
        short* dst = ob0 + (((size_t)(bb * H_ + h)) * T_ + t) * 64;
        #pragma unroll
        for (int ni = 0; ni < 2; ++ni) {
          int d = ni * 16 + ec;
          float c = cs[t * 32 + d] * SC2_, s = sn[t * 32 + d] * SC2_;
          float x0 = acc[mi][ni][r], x1 = acc[mi][ni + 2][r];
          dst[d]      = f2bf(x0 * c - x1 * s);
          dst[d + 32] = f2bf(x1 * c + x0 * s);
        }
      }
  } else if (cb == 768) {
    // fused LayerNorm -> ckv (row-major) + ckvT [B][64][T] via stride-40 LDS
    short* Wl = SM + w * 2560;          // 64 d-rows x 40 shorts, wave-private
    int bb = m0 >> 11;
    int dl = lane >> 2, tlo = (lane & 3) * 8;
    #pragma unroll
    for (int hp = 0; hp < 2; ++hp) {
      #pragma unroll
      for (int mi2 = 0; mi2 < 2; ++mi2) {
        int mi = hp * 2 + mi2;
        short vb[4][4];                 // [r][ni], static-indexed -> regs
        #pragma unroll
        for (int r = 0; r < 4; ++r) {
          float s = 0.f, s2 = 0.f;
          #pragma unroll
          for (int ni = 0; ni < 4; ++ni) { float v = acc[mi][ni][r]; s += v; s2 += v * v; }
          #pragma unroll
          for (int off = 1; off < 16; off <<= 1) {
            s  += __shfl_xor(s, off);
            s2 += __shfl_xor(s2, off);
          }
          float mu = s * (1.f / 64.f);
          float var = s2 * (1.f / 64.f) - mu * mu;
          float rstd = rsqrtf(var + 1e-5f);
          int row = m0 + wr * 64 + mi * 16 + er + r;
          #pragma unroll
          for (int ni = 0; ni < 4; ++ni) {
            int d = ni * 16 + ec;
            short q = f2bf((acc[mi][ni][r] - mu) * rstd * bias[d] + bias2[d]);
            vb[r][ni] = q;
            ob1[(size_t)row * 64 + d] = q;
          }
        }
        int tl0 = mi2 * 16 + er;
        #pragma unroll
        for (int ni = 0; ni < 4; ++ni) {
          int d = ni * 16 + ec;
          uint2 uu;
          uu.x = (unsigned)(unsigned short)vb[0][ni] | ((unsigned)(unsigned short)vb[1][ni] << 16);
          uu.y = (unsigned)(unsigned short)vb[2][ni] | ((unsigned)(unsigned short)vb[3][ni] << 16);
          *(uint2*)&Wl[d * 40 + tl0] = uu;
        }
      }
      int tg0 = (m0 & (T_ - 1)) + wr * 64 + hp * 32;
      #pragma unroll
      for (int j = 0; j < 4; ++j) {
        int d = j * 16 + dl;
        uint4 vv = *(const uint4*)&Wl[d * 40 + tlo];
        *(uint4*)&obT[((size_t)(bb * 64 + d)) * T_ + tg0 + tlo] = vv;
      }
    }
  }
  // cb==832: garbage pad tile, no output
}

// ---------------- gemm1: k = rope(ckv @ Wuk), single K-step (K=64) ----------
__global__ __launch_bounds__(256) void gemm1_k(
    const short* __restrict__ A, const short* __restrict__ Bt,
    short* __restrict__ ob0,
    const float* __restrict__ cs, const float* __restrict__ sn)
{
  constexpr int K = 64;
  __shared__ short SM[2 * 8192];        // As 16KB | Bs 16KB
  short* As = SM;
  short* Bs = SM + 8192;
  const int m0 = blockIdx.x * 128;
  const int n0 = blockIdx.y * 128;
  const int tid = threadIdx.x, lane = tid & 63, w = tid >> 6;
  const int wr = w >> 1, wc = w & 1;
  const int fr = lane & 15, fk = (lane >> 4) * 8;
  const int rstage = lane >> 3, cstage = (lane & 7) * 8;

  f32x4 acc[4][4] = {};

  #pragma unroll
  for (int i = 0; i < 4; ++i) {
    int c = w * 4 + i;
    int r = c * 8 + rstage;
    gload_lds16(&A[(size_t)(m0 + r) * K + cstage], As + c * 512);
    gload_lds16(&Bt[(size_t)(n0 + r) * K + cstage], Bs + c * 512);
  }
  __syncthreads();
  #pragma unroll
  for (int kk = 0; kk < 64; kk += 32) {
    bf16x8 a[4], b[4];
    #pragma unroll
    for (int mi = 0; mi < 4; ++mi)
      a[mi] = *(const bf16x8*)&As[(wr * 64 + mi * 16 + fr) * 64 + kk + fk];
    #pragma unroll
    for (int ni = 0; ni < 4; ++ni)
      b[ni] = *(const bf16x8*)&Bs[(wc * 64 + ni * 16 + fr) * 64 + kk + fk];
    #pragma unroll
    for (int mi = 0; mi < 4; ++mi)
      #pragma unroll
      for (int ni = 0; ni < 4; ++ni)
        acc[mi][ni] = __builtin_amdgcn_mfma_f32_16x16x32_bf16(a[mi], b[ni], acc[mi][ni], 0, 0, 0);
  }

  const int er = (lane >> 4) * 4, ec = lane & 15;
  const int cb = n0 + wc * 64;          // < 768 always
  int h = cb >> 6;
  #pragma unroll
  for (int mi = 0; mi < 4; ++mi)
    #pragma unroll
    for (int r = 0; r < 4; ++r) {
      int row = m0 + wr * 64 + mi * 16 + er + r;
      int t = row & (T_ - 1), bb = row >> 11;
      short* dst = ob0 + (((size_t)(bb * H_ + h)) * T_ + t) * 64;
      #pragma unroll
      for (int ni = 0; ni < 2; ++ni) {
        int d = ni * 16 + ec;
        float c = cs[t * 32 + d], s = sn[t * 32 + d];
        float x0 = acc[mi][ni][r], x1 = acc[mi][ni + 2][r];
        dst[d]      = f2bf(x0 * c - x1 * s);
        dst[d + 32] = f2bf(x1 * c + x0 * s);
      }
    }
}

// ---------------- attn (v9, verified body): V = ckv^T shared per batch ------
// Z_h = softmax(qk^T) @ ckv -> att[(b,t), h*64+r]; out GEMM applies Wvo.
// Balanced waves: wave w owns q-tile 4u+w; LPT dispatch (u = 15-blockIdx.y).
// Double-buffered K/V staging, in-register P via cvt_pk+permlane32_swap,
// deferred l-reduction, setprio around MFMA.
// 32x32 C/D layout (m74/m101): col=lane&31, row=(reg&3)+8*(reg>>2)+4*(lane>>5).
__global__ __launch_bounds__(256) void attn_mfma(
    const short* __restrict__ qgl, const short* __restrict__ kg,
    const short* __restrict__ vtg, short* __restrict__ o)
{
  __shared__ short SMa[2][2][8 * 512];   // 32 KB total

  const int bh = blockIdx.x;           // 0..47
  const int u  = 15 - blockIdx.y;      // LPT: longest block (u=15) first
  const int tid = threadIdx.x, lane = tid & 63, w = tid >> 6;
  const int q32 = lane & 31, half = lane >> 5;
  const int b = bh / H_, h = bh - b * H_;
  const short* kb  = kg  + (size_t)bh * T_ * 64;
  const short* vtb = vtg + (size_t)b * 64 * T_;   // ckv^T, shared by 12 heads

  const int wq = 4 * u + w;            // this wave's 32-row q-tile (0..63)
  const int q0 = wq * 32;
  const int last_w = (wq >> 1) * 64;   // diagonal k-tile start for this wave
  const int qidx = q0 + q32;
  const int kend = (2 * u + 1) * 64;   // block stages k-tiles 0..2u+1

  const short* qrow = qgl + ((size_t)bh * T_ + qidx) * 64;
  bf16x8 bq[4];
  #pragma unroll
  for (int ks = 0; ks < 4; ++ks)
    bq[ks] = *(const bf16x8*)&qrow[ks * 16 + half * 8];

  f32x16 oacc[2] = {};
  float lrun = 0.f;

  auto stage = [&](int buf, int kt) {
    #pragma unroll
    for (int i = 0; i < 2; ++i) {      // wave w stages chunks {2w, 2w+1}
      int c = w * 2 + i;
      int kh = c >> 2, ks = c & 3;
      gload_lds16(kb + (size_t)(kt + kh * 32 + q32) * 64 + ks * 16 + half * 8,
                  &SMa[buf][0][c * 512]);
      gload_lds16(vtb + (size_t)(kh * 32 + q32) * T_ + kt + ks * 16 + half * 8,
                  &SMa[buf][1][c * 512]);
    }
  };

  stage(0, 0);
  __syncthreads();                     // buf0 ready

  int cur = 0;
  for (int kt = 0; kt <= kend; kt += 64) {
    if (kt + 64 <= kend) stage(cur ^ 1, kt + 64);   // async prefetch next tile

    if (kt <= last_w) {
      const short* Kc = &SMa[cur][0][0];
      const short* Vc = &SMa[cur][1][0];
      const bool diag = (kt == last_w);
      const int dkh = diag ? (wq & 1) : 2;  // which kh is diagonal-masked
      const bool skip1 = diag && ((wq & 1) == 0);

      bf16x8 bp[4];
      #pragma unroll
      for (int kh = 0; kh < 2; ++kh) {
        if (kh == 1 && skip1) break;    // fully-masked upper half of diag tile
        f32x16 sacc = {};
        __builtin_amdgcn_s_setprio(1);
        #pragma unroll
        for (int ks = 0; ks < 4; ++ks) {
          bf16x8 a = *(const bf16x8*)&Kc[(kh * 4 + ks) * 512 + lane * 8];
          sacc = __builtin_amdgcn_mfma_f32_32x32x16_bf16(a, bq[ks], sacc, 0, 0, 0);
        }
        __builtin_amdgcn_s_setprio(0);
        float pv[16];
        if (kh != dkh) {
          #pragma unroll
          for (int r = 0; r < 16; ++r) pv[r] = fexp2(sacc[r]);
        } else {
          #pragma unroll
          for (int r = 0; r < 16; ++r) {
            int key = kt + kh * 32 + (r & 3) + 8 * (r >> 2) + 4 * half;
            pv[r] = (key <= qidx) ? fexp2(sacc[r]) : 0.f;
          }
        }
        float t0 = (pv[0] + pv[1]) + (pv[2] + pv[3]);
        float t1 = (pv[4] + pv[5]) + (pv[6] + pv[7]);
        float t2 = (pv[8] + pv[9]) + (pv[10] + pv[11]);
        float t3 = (pv[12] + pv[13]) + (pv[14] + pv[15]);
        lrun += (t0 + t1) + (t2 + t3);
        unsigned l0 = pk_bf16(pv[0],  pv[1]),  h0 = pk_bf16(pv[2],  pv[3]);
        unsigned l1 = pk_bf16(pv[4],  pv[5]),  h1 = pk_bf16(pv[6],  pv[7]);
        unsigned l2 = pk_bf16(pv[8],  pv[9]),  h2 = pk_bf16(pv[10], pv[11]);
        unsigned l3 = pk_bf16(pv[12], pv[13]), h3 = pk_bf16(pv[14], pv[15]);
        pswap(l0, l1); pswap(h0, h1);
        pswap(l2, l3); pswap(h2, h3);
        union { unsigned u[4]; bf16x8 v; } f0, f1;
        f0.u[0] = l0; f0.u[1] = h0; f0.u[2] = l1; f0.u[3] = h1;
        f1.u[0] = l2; f1.u[1] = h2; f1.u[2] = l3; f1.u[3] = h3;
        bp[2 * kh + 0] = f0.v;
        bp[2 * kh + 1] = f1.v;
      }

      __builtin_amdgcn_s_setprio(1);
      #pragma unroll
      for (int ks = 0; ks < 2; ++ks)
        #pragma unroll
        for (int dt = 0; dt < 2; ++dt) {
          bf16x8 av = *(const bf16x8*)&Vc[(dt * 4 + ks) * 512 + lane * 8];
          oacc[dt] = __builtin_amdgcn_mfma_f32_32x32x16_bf16(av, bp[ks], oacc[dt], 0, 0, 0);
        }
      if (!skip1) {
        #pragma unroll
        for (int ks = 2; ks < 4; ++ks)
          #pragma unroll
          for (int dt = 0; dt < 2; ++dt) {
            bf16x8 av = *(const bf16x8*)&Vc[(dt * 4 + ks) * 512 + lane * 8];
            oacc[dt] = __builtin_amdgcn_mfma_f32_32x32x16_bf16(av, bp[ks], oacc[dt], 0, 0, 0);
          }
      }
      __builtin_amdgcn_s_setprio(0);
    }

    __syncthreads();
    cur ^= 1;
  }

  float ltot = lrun + __shfl_xor(lrun, 32);
  float inv = 1.f / ltot;
  short* Pw = &SMa[0][0][0] + w * 2304;   // 32 rows x 72 shorts per wave
  #pragma unroll
  for (int dt = 0; dt < 2; ++dt)
    #pragma unroll
    for (int g2 = 0; g2 < 4; ++g2) {
      uint2 uu;
      uu.x = pk_bf16(oacc[dt][4 * g2 + 0] * inv, oacc[dt][4 * g2 + 1] * inv);
      uu.y = pk_bf16(oacc[dt][4 * g2 + 2] * inv, oacc[dt][4 * g2 + 3] * inv);
      *(uint2*)&Pw[q32 * 72 + dt * 32 + 8 * g2 + 4 * half] = uu;
    }
  int row = lane >> 1, seg = lane & 1;
  int t = q0 + row;
  short* orow = o + ((size_t)(b * T_ + t)) * HD_ + h * 64 + seg * 32;
  #pragma unroll
  for (int i = 0; i < 4; ++i) {
    uint4 vv = *(const uint4*)&Pw[row * 72 + seg * 32 + i * 8];
    *(uint4*)&orow[i * 8] = vv;
  }
}

// ---------------- out = Z @ Wvo + bo: 128x64 tile, double-buffered -----------
__global__ __launch_bounds__(256) void gemm_out(
    const short* __restrict__ A, const short* __restrict__ Bt,
    float* __restrict__ out0, const float* __restrict__ bias)
{
  constexpr int K = HD_, N = C_;
  __shared__ short SM[2 * (8192 + 4096)];  // 48KB: per buf As 16KB | Bs 8KB
  const int m0 = blockIdx.x * 128;
  const int n0 = blockIdx.y * 64;
  const int tid = threadIdx.x, lane = tid & 63, w = tid >> 6;
  const int fr = lane & 15, fk = (lane >> 4) * 8;
  const int rstage = lane >> 3, cstage = (lane & 7) * 8;

  f32x4 acc[2][4] = {};

  auto As = [&](int buf) -> short* { return SM + buf * 12288; };
  auto Bs = [&](int buf) -> short* { return SM + buf * 12288 + 8192; };

  auto stage = [&](int buf, int k0) {
    #pragma unroll
    for (int i = 0; i < 4; ++i) {          // A: 16 chunks
      int c = w * 4 + i;
      int r = c * 8 + rstage;
      gload_lds16(&A[(size_t)(m0 + r) * K + k0 + cstage], As(buf) + c * 512);
    }
    #pragma unroll
    for (int i = 0; i < 2; ++i) {          // B: 8 chunks
      int c = w * 2 + i;
      int r = c * 8 + rstage;
      gload_lds16(&Bt[(size_t)(n0 + r) * K + k0 + cstage], Bs(buf) + c * 512);
    }
  };

  stage(0, 0);
  __syncthreads();

  int buf = 0;
  for (int k0 = 0; k0 < K; k0 += 64) {
    if (k0 + 64 < K) stage(buf ^ 1, k0 + 64);
    #pragma unroll
    for (int kk = 0; kk < 64; kk += 32) {
      bf16x8 a[2], b[4];
      a[0] = *(const bf16x8*)&As(buf)[(w * 32 +      fr) * 64 + kk + fk];
      a[1] = *(const bf16x8*)&As(buf)[(w * 32 + 16 + fr) * 64 + kk + fk];
      #pragma unroll
      for (int ni = 0; ni < 4; ++ni)
        b[ni] = *(const bf16x8*)&Bs(buf)[(ni * 16 + fr) * 64 + kk + fk];
      #pragma unroll
      for (int mi = 0; mi < 2; ++mi)
        #pragma unroll
        for (int ni = 0; ni < 4; ++ni)
          acc[mi][ni] = __builtin_amdgcn_mfma_f32_16x16x32_bf16(a[mi], b[ni], acc[mi][ni], 0, 0, 0);
    }
    __syncthreads();
    buf ^= 1;
  }

  const int er = (lane >> 4) * 4, ec = lane & 15;
  #pragma unroll
  for (int mi = 0; mi < 2; ++mi)
    #pragma unroll
    for (int r = 0; r < 4; ++r) {
      int row = m0 + w * 32 + mi * 16 + er + r;
      #pragma unroll
      for (int ni = 0; ni < 4; ++ni) {
        int col = n0 + ni * 16 + ec;
        out0[(size_t)row * N + col] = acc[mi][ni][r] + bias[col];
      }
    }
}

// ---------------- launcher ----------------
extern "C" void kernel_launch(void* const* d_in, const int* in_sizes, int n_in,
                              void* d_out, int out_size, void* d_ws, size_t ws_size,
                              hipStream_t stream) {
  (void)in_sizes; (void)n_in; (void)out_size; (void)ws_size;
  const float* x     = (const float*)d_in[0];
  const float* Wq    = (const float*)d_in[1];
  const float* Wdown = (const float*)d_in[2];
  const float* ln_g  = (const float*)d_in[3];
  const float* ln_b  = (const float*)d_in[4];
  const float* Wup   = (const float*)d_in[5];
  const float* Wo    = (const float*)d_in[6];
  const float* bo    = (const float*)d_in[7];
  float* out = (float*)d_out;

  char* w = (char*)d_ws;
  short* W1T    = (short*)w;  w += (size_t)896 * C_    * 2;  // 832 used + pad
  short* WupT   = (short*)w;  w += (size_t)HD_ * R_    * 2;  // k-half only
  short* WvoT   = (short*)w;  w += (size_t)C_ * HD_    * 2;  // absorbed V*Wo
  short* ckv    = (short*)w;  w += (size_t)BT_ * R_    * 2;
  short* ckvT   = (short*)w;  w += (size_t)B_ * R_ * T_ * 2; // V for attn
  short* qb     = (short*)w;  w += (size_t)BT_ * HD_   * 2;
  short* kb     = (short*)w;  w += (size_t)BT_ * HD_   * 2;
  short* att    = (short*)w;  w += (size_t)BT_ * HD_   * 2;  // Z (latent PV)
  float* cs_t   = (float*)w;  w += (size_t)T_ * 32 * 4;
  float* sn_t   = (float*)w;  w += (size_t)T_ * 32 * 4;

  prep_conv<<<1312, 256, 0, stream>>>(Wq, Wdown, Wup, Wo,
                                      W1T, WupT, WvoT, cs_t, sn_t);

  // q (*SC2, +rope) and LN(ckv) + ckv^T in ONE pass over x
  gemm0_k<<<dim3(BT_/128, 7), 256, 0, stream>>>(
      x, W1T, ln_g, ln_b, qb, ckv, ckvT, cs_t, sn_t);

  // k = rope(ckv @ Wuk) only (V absorbed)
  gemm1_k<<<dim3(BT_/128, 6), 256, 0, stream>>>(
      ckv, WupT, kb, cs_t, sn_t);

  // attn over latent V = ckv (shared across heads)
  attn_mfma<<<dim3(B_*H_, 16), 256, 0, stream>>>(qb, kb, ckvT, att);

  // out = Z @ Wvo + bo
  gemm_out<<<dim3(BT_/128, 12), 256, 0, stream>>>(att, WvoT, out, bo);
}